// Round 6
// baseline (4672.942 us; speedup 1.0000x reference)
//
#include <hip/hip_runtime.h>

typedef _Float16 f16;
typedef _Float16 f16x8 __attribute__((ext_vector_type(8)));
typedef float    f32x4 __attribute__((ext_vector_type(4)));

#define SEQ   2048
#define BATCH 64
#define EMBED 256
#define HID   256
#define NC    1024            // 4 gates * HID

// fast transcendentals (1-instr HW ops)
__device__ __forceinline__ float fexp2(float x){ float r; asm("v_exp_f32 %0, %1" : "=v"(r) : "v"(x)); return r; }
__device__ __forceinline__ float frcp (float x){ float r; asm("v_rcp_f32 %0, %1" : "=v"(r) : "v"(x)); return r; }
__device__ __forceinline__ float sigm_f(float y){ return frcp(1.f + fexp2(y * -1.44269504f)); }
__device__ __forceinline__ float tanh_f(float y){ return 2.f*frcp(1.f + fexp2(y * -2.88539009f)) - 1.f; }

__device__ __forceinline__ void gload_lds4(const void* g, void* s) {
  __builtin_amdgcn_global_load_lds((const __attribute__((address_space(1))) void*)g,
                                   (__attribute__((address_space(3))) void*)s, 4, 0, 0);
}

// ---------------------------------------------------------------------------
// prep_w: f16 transposed weights. Wx_t/Wh_t [1024 col][256 k].
// ---------------------------------------------------------------------------
__global__ __launch_bounds__(256) void prep_w(
    const float* __restrict__ Wix, const float* __restrict__ Wih,
    const float* __restrict__ Wfx, const float* __restrict__ Wfh,
    const float* __restrict__ Wgx, const float* __restrict__ Wgh,
    const float* __restrict__ Wox, const float* __restrict__ Woh,
    f16* __restrict__ Wx_t, f16* __restrict__ Wh_t)
{
  int tid = blockIdx.x*256 + threadIdx.x;
  const float* WX[4] = {Wix, Wfx, Wgx, Wox};
  const float* WH[4] = {Wih, Wfh, Wgh, Woh};
  int which = tid >> 15;          // 0 -> Wx_t, 1 -> Wh_t
  int j  = (tid >> 5) & 1023;     // output column (gate*256 + unit)
  int ko = tid & 31;              // k-octet
  const float* src = (which ? WH : WX)[j >> 8];
  int u = j & 255;
  f16x8 v;
  #pragma unroll
  for (int q = 0; q < 8; ++q) v[q] = (f16)src[(ko*8+q)*HID + u];
  *(f16x8*)((which ? Wh_t : Wx_t) + (size_t)j*256 + ko*8) = v;
}

// ---------------------------------------------------------------------------
// gemm_x (unchanged from R5)
// ---------------------------------------------------------------------------
__global__ __launch_bounds__(256) void gemm_x(
    const float* __restrict__ emb, const f16* __restrict__ Bt,
    const float* __restrict__ b0, const float* __restrict__ b1,
    const float* __restrict__ b2, const float* __restrict__ b3,
    f16* __restrict__ Xo)
{
  __shared__ f16 Al[64*256];
  __shared__ f16 Bl[64*256];
  int wg = blockIdx.x;
  int R0 = (wg >> 4) * 64;
  int C0 = (wg & 15) * 64;
  int tid = threadIdx.x;

  #pragma unroll
  for (int j = 0; j < 8; ++j) {
    int c = tid + j*256; int row = c >> 5, ci = c & 31;
    const float* ap = emb + (size_t)(R0+row)*EMBED + ci*8;
    f32x4 a0 = *(const f32x4*)ap;
    f32x4 a1 = *(const f32x4*)(ap + 4);
    f16x8 v;
    #pragma unroll
    for (int q = 0; q < 4; ++q) { v[q] = (f16)a0[q]; v[q+4] = (f16)a1[q]; }
    *(f16x8*)((char*)Al + row*512 + ((ci*16) ^ ((row&7)<<4))) = v;
    f16x8 vb = *(const f16x8*)(Bt + (size_t)(C0+row)*256 + ci*8);
    *(f16x8*)((char*)Bl + row*512 + ((ci*16) ^ ((row&7)<<4))) = vb;
  }
  __syncthreads();

  int w = tid >> 6, l = tid & 63, lr = l & 15, lg = l >> 4;
  const float* bp = (C0 < 256) ? b0 : (C0 < 512) ? b1 : (C0 < 768) ? b2 : b3;
  int ub = (C0 & 255) + lr;
  f32x4 cf[4];
  #pragma unroll
  for (int nt = 0; nt < 4; ++nt) { float bv = bp[ub + nt*16]; cf[nt] = (f32x4){bv,bv,bv,bv}; }

  #pragma unroll
  for (int kf = 0; kf < 8; ++kf) {
    int arow = w*16 + lr;
    f16x8 af = *(const f16x8*)((char*)Al + arow*512 + ((kf*64 + lg*16) ^ ((arow&7)<<4)));
    #pragma unroll
    for (int nt = 0; nt < 4; ++nt) {
      int brow = nt*16 + lr;
      f16x8 bf = *(const f16x8*)((char*)Bl + brow*512 + ((kf*64 + lg*16) ^ ((brow&7)<<4)));
      cf[nt] = __builtin_amdgcn_mfma_f32_16x16x32_f16(af, bf, cf[nt], 0, 0, 0);
    }
  }
  #pragma unroll
  for (int nt = 0; nt < 4; ++nt)
    #pragma unroll
    for (int r = 0; r < 4; ++r) {
      int row = R0 + w*16 + lg*4 + r;
      int col = C0 + nt*16 + lr;
      Xo[(size_t)row*NC + col] = (f16)cf[nt][r];
    }
}

// ---------------------------------------------------------------------------
// lstm_rec: 256 WGs = 64 batches x 4 quarters. WG (b,q) owns units
// [q*64,(q+1)*64) with all 4 gates (local cols j=0..255: g=j>>6, u'=j&63,
// global col = g*256 + q*64 + u'). W_h slice lives ENTIRELY in registers:
// per wave WB[2][8] f16x8 = 64 VGPR (wave w: g=w>>1, u' base (w&1)*32).
// Per step: MFMA matvec (h replicated in A rows, 16 MFMA/wave),
// island h-exchange via relaxed AGENT-scope atomics:
//   writer (wave0): h-slice u32x32 -> hg[(t+1)&1], vmcnt(0), flag[b][q]=t+1
//   readers (waves 2,3): spin flag>=t, load 3 slices, ds_write hl[t&1]
// Flags zeroed each launch by hipMemsetAsync (graph-replay determinism).
// x prefetched 2 ahead via global_load_lds (waves 4,5), 3 rotating bufs.
// ---------------------------------------------------------------------------
__global__ __launch_bounds__(512) void lstm_rec(
    const f16* __restrict__ Wh_t, const f16* __restrict__ X,
    unsigned* __restrict__ flag, unsigned* __restrict__ hg,
    float* __restrict__ out)
{
  __shared__ unsigned hlw[2][128];   // h as f16[2][256]
  __shared__ f16      xs16[3][256];  // rotating x buffers (local cols)
  __shared__ float    act[4][64];    // [gate][unit']

  int blk = blockIdx.x;
  int b = blk & 63, q = blk >> 6;
  int tid = threadIdx.x;
  int w = tid >> 6, l = tid & 63, lr = l & 15, lg = l >> 4;
  int g = w >> 1;
  f16* hl16 = (f16*)hlw;

  // ---- prologue ----
  if (tid < 256) ((unsigned*)hlw)[tid] = 0;   // h(0) = 0 both parities
  // x(0), x(1) prefetch (waves 4,5; lane-linear LDS dest)
  if (tid >= 256 && tid < 384) {
    int k = tid - 256;                     // 0..127, u32 slot k
    int j = 2*k;
    int gcol = (j >> 6)*256 + q*64 + (j & 63);
    f16* dst0 = &xs16[0][(tid >= 320) ? 128 : 0];
    f16* dst1 = &xs16[1][(tid >= 320) ? 128 : 0];
    gload_lds4(X + (size_t)b*NC + gcol,            dst0);
    gload_lds4(X + (size_t)(BATCH + b)*NC + gcol,  dst1);
  }
  // WB: per-wave register weights, 2 n-tiles x 8 kf
  f16x8 WB[2][8];
  #pragma unroll
  for (int nt = 0; nt < 2; ++nt) {
    int col = g*256 + q*64 + (w&1)*32 + nt*16 + lr;
    const f16* basep = Wh_t + (size_t)col*256 + lg*8;
    #pragma unroll
    for (int kf = 0; kf < 8; ++kf) WB[nt][kf] = *(const f16x8*)(basep + kf*32);
  }
  #pragma unroll
  for (int nt = 0; nt < 2; ++nt)
    #pragma unroll
    for (int kf = 0; kf < 8; ++kf)
      asm volatile("" : "+v"(WB[nt][kf]));

  float c0 = 0.f, c1 = 0.f;
  asm volatile("s_waitcnt lgkmcnt(0)" ::: "memory");
  __builtin_amdgcn_s_barrier();

  int xc = 0;
  for (int t = 0; t < SEQ; ++t) {
    int cur = t & 1;
    // 1: x prefetch t+2 (waves 4,5)
    if (tid >= 256 && tid < 384 && t + 2 < SEQ) {
      int k = tid - 256; int j = 2*k;
      int gcol = (j >> 6)*256 + q*64 + (j & 63);
      int xn2 = (xc == 0) ? 2 : xc - 1;
      f16* dst = &xs16[xn2][(tid >= 320) ? 128 : 0];
      gload_lds4(X + ((size_t)(t+2)*BATCH + b)*NC + gcol, dst);
    }
    // 2: island h-exchange (waves 2,3): poll + stage others' slices
    if (t > 0 && tid >= 128 && tid < 256) {
      int qo = (q + 1 + l) & 3;      // meaningful for l<3
      unsigned ft;
      do {
        ft = 0xFFFFFFFFu;
        if (l < 3)
          ft = __hip_atomic_load(&flag[b*4 + qo], __ATOMIC_RELAXED, __HIP_MEMORY_SCOPE_AGENT);
      } while (!__all(ft >= (unsigned)t));
      int tidp = tid - 128;
      if (tidp < 96) {
        int s = tidp >> 5, m = tidp & 31;
        int q2 = (q + 1 + s) & 3;
        unsigned v = __hip_atomic_load(&hg[(size_t)cur*8192 + b*128 + q2*32 + m],
                                       __ATOMIC_RELAXED, __HIP_MEMORY_SCOPE_AGENT);
        hlw[cur][q2*32 + m] = v;
      }
    }
    // 3: rendezvous — hl staged, x(t) landed
    if (w == 4 || w == 5) {
      if (t < SEQ-2) asm volatile("s_waitcnt vmcnt(2) lgkmcnt(0)" ::: "memory");
      else           asm volatile("s_waitcnt vmcnt(0) lgkmcnt(0)" ::: "memory");
    } else {
      asm volatile("s_waitcnt lgkmcnt(0)" ::: "memory");
    }
    __builtin_amdgcn_s_barrier();

    // 4: cf init from x_t
    f32x4 cf[2];
    #pragma unroll
    for (int nt = 0; nt < 2; ++nt) {
      float xv = (float)xs16[xc][w*32 + nt*16 + lr];
      cf[nt] = (f32x4){xv, xv, xv, xv};
    }
    // 5: MFMA over full K from registers
    #pragma unroll
    for (int kf = 0; kf < 8; ++kf) {
      f16x8 ha = *(const f16x8*)(&hl16[cur*256 + kf*32 + lg*8]);
      cf[0] = __builtin_amdgcn_mfma_f32_16x16x32_f16(ha, WB[0][kf], cf[0], 0, 0, 0);
      cf[1] = __builtin_amdgcn_mfma_f32_16x16x32_f16(ha, WB[1][kf], cf[1], 0, 0, 0);
    }
    // 6: activations -> act[g][u']
    if (l < 16) {
      float y0 = cf[0][0], y1 = cf[1][0];
      float a0 = (g == 2) ? tanh_f(y0) : sigm_f(y0);
      float a1 = (g == 2) ? tanh_f(y1) : sigm_f(y1);
      act[g][(w&1)*32 + lr]      = a0;
      act[g][(w&1)*32 + 16 + lr] = a1;
    }
    asm volatile("s_waitcnt lgkmcnt(0)" ::: "memory");
    __builtin_amdgcn_s_barrier();

    // 7: c/h update (tid<32, 2 units each), publish, out store
    if (tid < 32) {
      int u0 = 2*tid, u1 = u0 + 1;
      float i0 = act[0][u0], f0 = act[1][u0], g0 = act[2][u0], o0 = act[3][u0];
      float i1 = act[0][u1], f1 = act[1][u1], g1 = act[2][u1], o1 = act[3][u1];
      c0 = f0*c0 + i0*g0;
      c1 = f1*c1 + i1*g1;
      float h0 = o0*tanh_f(c0);
      float h1 = o1*tanh_f(c1);
      f16 ha_ = (f16)h0, hb_ = (f16)h1;
      unsigned hp = (unsigned)*(unsigned short*)&ha_ | ((unsigned)*(unsigned short*)&hb_ << 16);
      hlw[cur ^ 1][q*32 + tid] = hp;                      // own slice, next parity
      __hip_atomic_store(&hg[(size_t)(cur^1)*8192 + b*128 + q*32 + tid], hp,
                         __ATOMIC_RELAXED, __HIP_MEMORY_SCOPE_AGENT);
      float2 o2 = {h0, h1};
      *(float2*)&out[((size_t)t*BATCH + b)*HID + q*64 + 2*tid] = o2;
    }
    if (w == 0) { asm volatile("s_waitcnt vmcnt(0)" ::: "memory"); }
    if (tid == 0)
      __hip_atomic_store(&flag[b*4 + q], (unsigned)(t + 1),
                         __ATOMIC_RELAXED, __HIP_MEMORY_SCOPE_AGENT);

    xc = (xc == 2) ? 0 : xc + 1;
  }
}

// ---------------------------------------------------------------------------
extern "C" void kernel_launch(void* const* d_in, const int* in_sizes, int n_in,
                              void* d_out, int out_size, void* d_ws, size_t ws_size,
                              hipStream_t stream) {
  const float* emb = (const float*)d_in[0];
  const float* Wix = (const float*)d_in[1];
  const float* Wih = (const float*)d_in[2];
  const float* bi  = (const float*)d_in[3];
  const float* Wfx = (const float*)d_in[4];
  const float* Wfh = (const float*)d_in[5];
  const float* bf  = (const float*)d_in[6];
  const float* Wgx = (const float*)d_in[7];
  const float* Wgh = (const float*)d_in[8];
  const float* bg  = (const float*)d_in[9];
  const float* Wox = (const float*)d_in[10];
  const float* Woh = (const float*)d_in[11];
  const float* bo  = (const float*)d_in[12];

  char* ws = (char*)d_ws;
  f16*      Wx_t  = (f16*)(ws);                 //   524288 B
  f16*      Wh_t  = (f16*)(ws + 524288);        //   524288 B
  unsigned* flags = (unsigned*)(ws + 1048576);  //     1024 B
  unsigned* hg    = (unsigned*)(ws + 1052672);  //    65536 B (2*64*128 u32)
  f16*      Xp    = (f16*)(ws + 1179648);       // 268435456 B

  hipMemsetAsync(flags, 0, 1024, stream);
  prep_w  <<<256,   256, 0, stream>>>(Wix, Wih, Wfx, Wfh, Wgx, Wgh, Wox, Woh,
                                      Wx_t, Wh_t);
  gemm_x  <<<32768, 256, 0, stream>>>(emb, Wx_t, bi, bf, bg, bo, Xp);
  lstm_rec<<<256,   512, 0, stream>>>(Wh_t, Xp, flags, hg, (float*)d_out);
}